// Round 4
// baseline (1492.634 us; speedup 1.0000x reference)
//
#include <hip/hip_runtime.h>
#include <stdint.h>

#define T_ 128
#define B_ 256
#define D_ 512
#define H_ 768
#define NG 3072   // 4*H
#define OUT_ 60

#define GRP_WGS 48   // strips per batch group; 4 groups x 48 = 192 WGs
#define SCRB 98304   // bytes of one group's h (64 rows x 768 x bf16)

using bf16x8 = __attribute__((ext_vector_type(8))) __bf16;
using f32x4  = __attribute__((ext_vector_type(4))) float;
using u32x4  = __attribute__((ext_vector_type(4))) unsigned int;

// ---------------- ws layout (bytes) ----------------
#define OFF_XPK  ((size_t)0)                        // x frag-packed bf16
#define OFF_WIPK (OFF_XPK + (size_t)T_*B_*D_*2)     // W_ih frag-packed
#define OFF_WHH  (OFF_WIPK + (size_t)NG*D_*2)       // W_hh bf16 linear [4H][H]
#define OFF_H    (OFF_WHH + (size_t)NG*H_*2)        // ushort[2*B*H] h double buffer
#define OFF_HT   (OFF_H   + (size_t)2*B_*H_*2)      // float[B*H] final h
#define OFF_BAR  (OFF_HT  + (size_t)B_*H_*4)        // uint[8192]: flags + counters
#define OFF_SCR  (OFF_BAR + 32768)                  // per-(xcd,grp) h scratch, dbuf
#define OFF_END  (OFF_SCR + (size_t)32*2*SCRB)      // +6.29 MB

// bar[] u32 indices
#define BAR_FLAG(gg,ss) (((gg)*48 + (ss)) * 16)
#define BAR_INIT  3200
#define BAR_MEM(id)  (3328 + (id)*16)
#define BAR_STEP(id) (3968 + (id)*16)

__device__ __forceinline__ unsigned short f2bf(float f) {
  union { float f; unsigned u; } v; v.f = f;
  unsigned r = (v.u + 0x7fffu + ((v.u >> 16) & 1u)) >> 16;  // RNE
  return (unsigned short)r;
}
__device__ __forceinline__ float sigf(float x) {
  return __builtin_amdgcn_rcpf(1.0f + __expf(-x));
}
__device__ __forceinline__ float tanhf_(float x) {
  return 2.0f * __builtin_amdgcn_rcpf(1.0f + __expf(-2.0f * x)) - 1.0f;
}
__device__ __forceinline__ void coh_store8(void* p, unsigned long long v) {
  __hip_atomic_store((unsigned long long*)p, v, __ATOMIC_RELAXED, __HIP_MEMORY_SCOPE_SYSTEM);
}
__device__ __forceinline__ void coh_store4(unsigned* p, unsigned v) {
  __hip_atomic_store(p, v, __ATOMIC_RELAXED, __HIP_MEMORY_SCOPE_SYSTEM);
}
__device__ __forceinline__ unsigned coh_load4(const unsigned* p) {
  return __hip_atomic_load(p, __ATOMIC_RELAXED, __HIP_MEMORY_SCOPE_SYSTEM);
}
__device__ __forceinline__ unsigned sys_add(unsigned* p, unsigned v) {
  return __hip_atomic_fetch_add(p, v, __ATOMIC_RELAXED, __HIP_MEMORY_SCOPE_SYSTEM);
}
__device__ __forceinline__ unsigned get_xcd() {
  unsigned x;
  asm volatile("s_getreg_b32 %0, hwreg(HW_REG_XCC_ID)" : "=s"(x));
  return x & 7u;
}
// L2-local read (bypass L1 only) — serves from this XCD's L2, no fabric
template<int OFF>
__device__ __forceinline__ u32x4 l2_load16(const void* p) {
  u32x4 r;
  asm volatile("global_load_dwordx4 %0, %1, off offset:%c2 sc0"
               : "=v"(r) : "v"(p), "i"(OFF) : "memory");
  return r;
}
// fabric-coherent read (bypass L1+L2)
__device__ __forceinline__ u32x4 coh_load16dyn(const void* p) {
  u32x4 r;
  asm volatile("global_load_dwordx4 %0, %1, off sc0 sc1"
               : "=v"(r) : "v"(p) : "memory");
  return r;
}

// ---------------- phase A: pack/convert + init ----------------
__global__ void prep_kernel(const float* __restrict__ x,
                            const float* __restrict__ wihf,
                            const float* __restrict__ whhf,
                            uint8_t* __restrict__ ws) {
  ushort* xpk = (ushort*)(ws + OFF_XPK);
  ushort* wipk = (ushort*)(ws + OFF_WIPK);
  ushort* wh  = (ushort*)(ws + OFF_WHH);
  unsigned* hb = (unsigned*)(ws + OFF_H);
  unsigned* bar = (unsigned*)(ws + OFF_BAR);
  unsigned* scr = (unsigned*)(ws + OFF_SCR);
  const size_t tid = (size_t)blockIdx.x * blockDim.x + threadIdx.x;
  const size_t nth = (size_t)gridDim.x * blockDim.x;

  for (size_t c = tid; c < (size_t)T_*B_*D_/8; c += nth) {
    const float4 v0 = ((const float4*)x)[c*2];
    const float4 v1 = ((const float4*)x)[c*2+1];
    ushort4 o0, o1;
    o0.x=f2bf(v0.x); o0.y=f2bf(v0.y); o0.z=f2bf(v0.z); o0.w=f2bf(v0.w);
    o1.x=f2bf(v1.x); o1.y=f2bf(v1.y); o1.z=f2bf(v1.z); o1.w=f2bf(v1.w);
    const unsigned kf = ((unsigned)c & 63u) >> 2;
    const unsigned hi = (unsigned)c & 3u;
    const unsigned row = (unsigned)(c >> 6);          // t*256 + b
    const unsigned t = row >> 8, b = row & 255u;
    const unsigned g = b >> 6, w = (b >> 4) & 3u, l15 = b & 15u;
    const size_t dst = ((size_t)(((t*4u+g)*4u+w)*16u + kf)*64u + hi*16u + l15) * 8u;
    *(ushort4*)(xpk + dst)     = o0;
    *(ushort4*)(xpk + dst + 4) = o1;
  }
  for (size_t c = tid; c < (size_t)NG*D_/8; c += nth) {
    const float4 v0 = ((const float4*)wihf)[c*2];
    const float4 v1 = ((const float4*)wihf)[c*2+1];
    ushort4 o0, o1;
    o0.x=f2bf(v0.x); o0.y=f2bf(v0.y); o0.z=f2bf(v0.z); o0.w=f2bf(v0.w);
    o1.x=f2bf(v1.x); o1.y=f2bf(v1.y); o1.z=f2bf(v1.z); o1.w=f2bf(v1.w);
    const unsigned kf = ((unsigned)c & 63u) >> 2;
    const unsigned hi = (unsigned)c & 3u;
    const unsigned row = (unsigned)(c >> 6);          // gate-row 0..3071
    const unsigned q = row / 768u, rr = row - q*768u;
    const unsigned s = rr >> 4, l15 = rr & 15u;
    const size_t dst = ((size_t)((s*4u+q)*16u + kf)*64u + hi*16u + l15) * 8u;
    *(ushort4*)(wipk + dst)     = o0;
    *(ushort4*)(wipk + dst + 4) = o1;
  }
  for (size_t i = tid; i < (size_t)NG*H_/4; i += nth) {
    float4 v = ((const float4*)whhf)[i];
    ushort4 o; o.x=f2bf(v.x); o.y=f2bf(v.y); o.z=f2bf(v.z); o.w=f2bf(v.w);
    ((ushort4*)wh)[i] = o;
  }
  for (size_t i = tid; i < (size_t)2*B_*H_/2; i += nth) hb[i] = 0u;
  for (size_t i = tid; i < 8192; i += nth) bar[i] = 0u;
  for (size_t i = tid; i < (size_t)32*2*SCRB/4; i += nth) scr[i] = 0u;
}

// ---------------- phase C: persistent recurrence ----------------
// 192 WGs, 1/CU. Per WG: 64 batch rows x 16 h-cols, all 4 gates. W_hh in LDS.
// Per step: 48 strips post h (sc1) -> co-located WGs cooperatively fetch the
// group's 98KB ONCE per XCD into L2 scratch -> everyone reads via sc0 (L2 hits).
__global__ __launch_bounds__(256) void lstm_kernel(uint8_t* __restrict__ ws,
                                                   const float* __restrict__ bih,
                                                   const float* __restrict__ bhh) {
  const uint8_t* __restrict__ xpk = ws + OFF_XPK;
  const uint8_t* __restrict__ wipk = ws + OFF_WIPK;
  const uint8_t* __restrict__ wh  = ws + OFF_WHH;
  ushort* __restrict__ hb = (ushort*)(ws + OFF_H);
  float* __restrict__ hT = (float*)(ws + OFF_HT);
  unsigned* __restrict__ bar = (unsigned*)(ws + OFF_BAR);
  uint8_t* __restrict__ scr = ws + OFF_SCR;

  const int tid = threadIdx.x;
  const int lane = tid & 63;
  const int w = tid >> 6;
  const int g = blockIdx.x & 3;           // batch group
  const int s = blockIdx.x >> 2;          // h-strip 0..47
  const int rb0 = g * 64;
  const int colj = s*16 + (lane & 15);
  const int arowl = w*16 + (lane & 15);           // A-frag row, group-local
  const int crowl = w*16 + (lane >> 4)*4;         // C rows base, group-local
  const int ak = (lane >> 4) * 8;                 // A/B k-slot offset (elements)

  __shared__ ushort wlds[4*24*64*8];   // 96 KB, fragment-ordered W_hh
  __shared__ ushort hstage[64*16];     // 2 KB
  __shared__ unsigned initsh[2];
  for (int i = 0; i < 24; ++i) {
    const int c = tid + i*256;
    const int l = c & 63, q = (c >> 6) & 3, kf = c >> 8;
    const int grow = q*H_ + s*16 + (l & 15);
    const int gcolB = kf*64 + (l >> 4)*16;
    *(uint4*)((uint8_t*)wlds + (size_t)c*16) =
        *(const uint4*)(wh + (size_t)grow*(H_*2) + gcolB);
  }

  // ---- init: discover XCD membership (rank, nx) + one-time global barrier ----
  const unsigned xcd = get_xcd();
  const unsigned sid = xcd*4u + (unsigned)g;      // scratch id, 0..31
  if (tid == 0) {
    const unsigned r = sys_add(&bar[BAR_MEM(sid)], 1u);
    sys_add(&bar[BAR_INIT], 1u);
    while (coh_load4(&bar[BAR_INIT]) < 192u) __builtin_amdgcn_s_sleep(2);
    initsh[0] = r;
    initsh[1] = coh_load4(&bar[BAR_MEM(sid)]);
  }
  __syncthreads();
  const unsigned rank = initsh[0];
  const unsigned nx = initsh[1];
  const int chunks = (6144 + (int)nx - 1) / (int)nx;   // 16B chunks per WG

  float bias[4];
  #pragma unroll
  for (int q = 0; q < 4; ++q) bias[q] = bih[q*H_ + colj] + bhh[q*H_ + colj];

  float cc[4] = {0.f, 0.f, 0.f, 0.f};
  f32x4 acc[4];
  #pragma unroll
  for (int q = 0; q < 4; ++q) acc[q] = (f32x4){0.f,0.f,0.f,0.f};

  // phase-1 for t=0: acc[q] = x(0) @ W_ih^T
  {
    const u32x4* px = (const u32x4*)(xpk) + ((size_t)((0*4+g)*4+w)*16)*64 + lane;
    const u32x4* pw = (const u32x4*)(wipk) + ((size_t)(s*4)*16)*64 + lane;
    #pragma unroll
    for (int kf = 0; kf < 16; ++kf) {
      const u32x4 xr = px[kf*64];
      const bf16x8 xa = *(const bf16x8*)&xr;
      #pragma unroll
      for (int q = 0; q < 4; ++q) {
        const u32x4 wr = pw[(q*16 + kf)*64];
        acc[q] = __builtin_amdgcn_mfma_f32_16x16x32_bf16(xa, *(const bf16x8*)&wr, acc[q], 0, 0, 0);
      }
    }
  }

  const unsigned myflag = BAR_FLAG(g, s);
  const unsigned pollidx = BAR_FLAG(g, (lane < 48 ? lane : 47));

  for (int t = 0; t < T_; ++t) {
    if (t > 0) {
      // ---- global ready: all 48 strips of my group posted h(t) ----
      if (w == 0) {
        while (1) {
          const unsigned v = coh_load4(&bar[pollidx]);
          if (__all((int)(v >= (unsigned)t))) break;
          __builtin_amdgcn_s_sleep(1);
        }
      }
      __syncthreads();
      // ---- cooperative fetch: my slice of group h(t) -> local L2 scratch ----
      {
        const uint8_t* src = (const uint8_t*)hb + (size_t)(t & 1)*B_*H_*2 + (size_t)rb0*H_*2;
        uint8_t* dst = scr + (size_t)(sid*2u + (unsigned)(t & 1))*SCRB;
        const int c0 = (int)rank * chunks;
        const int c1 = (c0 + chunks < 6144) ? c0 + chunks : 6144;
        for (int cb = c0 + tid; cb < c1; cb += 256*8) {
          u32x4 tmp[8];
          #pragma unroll
          for (int k = 0; k < 8; ++k) {
            const int c = cb + k*256;
            if (c < c1) tmp[k] = coh_load16dyn(src + (size_t)c*16);
          }
          asm volatile("s_waitcnt vmcnt(0)" ::: "memory");
          #pragma unroll
          for (int k = 0; k < 8; ++k) {
            const int c = cb + k*256;
            if (c < c1) *(u32x4*)(dst + (size_t)c*16) = tmp[k];
          }
        }
        asm volatile("s_waitcnt vmcnt(0)" ::: "memory");  // scratch stores in L2
      }
      __syncthreads();
      if (tid == 0) {
        sys_add(&bar[BAR_STEP(sid)], 1u);
        const unsigned tgt = nx * (unsigned)t;
        while (coh_load4(&bar[BAR_STEP(sid)]) < tgt) __builtin_amdgcn_s_sleep(1);
      }
      __syncthreads();

      // ---- A-frags from L2-local scratch (sc0), then rec-MFMA ----
      const uint8_t* abase = scr + (size_t)(sid*2u + (unsigned)(t & 1))*SCRB
                              + (size_t)arowl*1536 + (size_t)ak*2;
      u32x4 ah[24];
      #define LOADH(i) ah[i] = l2_load16<(i)*64>(abase)
      LOADH(0); LOADH(1); LOADH(2); LOADH(3); LOADH(4); LOADH(5);
      LOADH(6); LOADH(7); LOADH(8); LOADH(9); LOADH(10); LOADH(11);
      LOADH(12); LOADH(13); LOADH(14); LOADH(15); LOADH(16); LOADH(17);
      LOADH(18); LOADH(19); LOADH(20); LOADH(21); LOADH(22); LOADH(23);
      #undef LOADH
      asm volatile("s_waitcnt vmcnt(0)" ::: "memory");
      __builtin_amdgcn_sched_barrier(0);
      #pragma unroll
      for (int kf = 0; kf < 24; ++kf) {
        const bf16x8 a = *(const bf16x8*)&ah[kf];
        #pragma unroll
        for (int q = 0; q < 4; ++q) {
          const bf16x8 b = *(const bf16x8*)((const uint8_t*)wlds +
                            (size_t)((kf*4 + q)*64 + lane)*16);
          acc[q] = __builtin_amdgcn_mfma_f32_16x16x32_bf16(a, b, acc[q], 0, 0, 0);
        }
      }
    }

    // ---- activations + state update ----
    float hv4[4];
    #pragma unroll
    for (int r = 0; r < 4; ++r) {
      const float iv = sigf(acc[0][r] + bias[0]);
      const float fv = sigf(acc[1][r] + bias[1]);
      const float gv = tanhf_(acc[2][r] + bias[2]);
      const float ov = sigf(acc[3][r] + bias[3]);
      const float cn = fv * cc[r] + iv * gv;
      cc[r] = cn;
      hv4[r] = ov * tanhf_(cn);
    }
    if (t == T_-1) {
      #pragma unroll
      for (int r = 0; r < 4; ++r)
        hT[(size_t)(rb0 + crowl + r)*H_ + colj] = hv4[r];
      break;
    }
    #pragma unroll
    for (int r = 0; r < 4; ++r)
      hstage[(crowl + r)*16 + (lane & 15)] = f2bf(hv4[r]);
    __syncthreads();
    {  // cooperative coherent h-store: 256 threads x one aligned 8B store
      const int row = tid >> 2, cg = tid & 3;
      const unsigned long long v = *(const unsigned long long*)&hstage[row*16 + cg*4];
      coh_store8(hb + (size_t)((t+1) & 1)*B_*H_ + (size_t)(rb0 + row)*H_ + s*16 + cg*4, v);
    }
    asm volatile("s_waitcnt vmcnt(0)" ::: "memory");
    __syncthreads();
    if (tid == 0) coh_store4(&bar[myflag], (unsigned)(t + 1));

    // ---- phase-1 for t+1 under the wait: acc = x(t+1) @ W_ih^T ----
    #pragma unroll
    for (int q = 0; q < 4; ++q) acc[q] = (f32x4){0.f,0.f,0.f,0.f};
    {
      const u32x4* px = (const u32x4*)(xpk) + ((size_t)(((t+1)*4+g)*4+w)*16)*64 + lane;
      const u32x4* pw = (const u32x4*)(wipk) + ((size_t)(s*4)*16)*64 + lane;
      #pragma unroll
      for (int kf = 0; kf < 16; ++kf) {
        const u32x4 xr = px[kf*64];
        const bf16x8 xa = *(const bf16x8*)&xr;
        #pragma unroll
        for (int q = 0; q < 4; ++q) {
          const u32x4 wr = pw[(q*16 + kf)*64];
          acc[q] = __builtin_amdgcn_mfma_f32_16x16x32_bf16(xa, *(const bf16x8*)&wr, acc[q], 0, 0, 0);
        }
      }
    }
  }
}

// ---------------- phase D: out = h_T @ W_fc^T + b_fc ----------------
__global__ __launch_bounds__(64) void fc_kernel(const uint8_t* __restrict__ ws,
                                                const float* __restrict__ wfc,
                                                const float* __restrict__ bfc,
                                                float* __restrict__ out) {
  const float* hT = (const float*)(ws + OFF_HT);
  const int b = blockIdx.x;
  const int lane = threadIdx.x;
  const float* hr = hT + (size_t)b*H_;
  float hv[12];
  #pragma unroll
  for (int i = 0; i < 12; ++i) hv[i] = hr[lane + i*64];
  for (int o = 0; o < OUT_; ++o) {
    const float* wr = wfc + (size_t)o*H_;
    float sum = 0.f;
    #pragma unroll
    for (int i = 0; i < 12; ++i) sum += hv[i] * wr[lane + i*64];
    #pragma unroll
    for (int off = 32; off; off >>= 1) sum += __shfl_xor(sum, off);
    if (lane == 0) out[(size_t)b*OUT_ + o] = sum + bfc[o];
  }
}

extern "C" void kernel_launch(void* const* d_in, const int* in_sizes, int n_in,
                              void* d_out, int out_size, void* d_ws, size_t ws_size,
                              hipStream_t stream) {
  const float* x   = (const float*)d_in[0];
  const float* wih = (const float*)d_in[1];
  const float* whh = (const float*)d_in[2];
  const float* bih = (const float*)d_in[3];
  const float* bhh = (const float*)d_in[4];
  const float* wfc = (const float*)d_in[5];
  const float* bfc = (const float*)d_in[6];
  uint8_t* ws = (uint8_t*)d_ws;
  float* out = (float*)d_out;

  prep_kernel<<<dim3(2048), dim3(256), 0, stream>>>(x, wih, whh, ws);
  lstm_kernel<<<dim3(192), dim3(256), 0, stream>>>(ws, bih, bhh);
  fc_kernel<<<dim3(256), dim3(64), 0, stream>>>(ws, wfc, bfc, out);
}

// Round 5
// 1141.001 us; speedup vs baseline: 1.3082x; 1.3082x over previous
//
#include <hip/hip_runtime.h>
#include <stdint.h>

#define T_ 128
#define B_ 256
#define D_ 512
#define H_ 768
#define OUT_ 60

using bf16x8 = __attribute__((ext_vector_type(8))) __bf16;
using f32x4  = __attribute__((ext_vector_type(4))) float;
using u32x4  = __attribute__((ext_vector_type(4))) unsigned int;

// ---------------- ws layout (bytes) ----------------
// x frag-packed:   chunk (((t*8+g)*2+mt)*16+kf)*64 + kslot*16 + (b&15)  [16B each]
// W_ih frag-packed: chunk ((s*16+kf)*6+nt)*64 + L
// W_hh frag-packed: chunk ((s*24+kf)*6+nt)*64 + L
#define OFF_XPK  ((size_t)0)                        // 33,554,432
#define OFF_WIPK (OFF_XPK + (size_t)T_*B_*D_*2)     //  3,145,728
#define OFF_WHPK (OFF_WIPK + (size_t)4*H_*D_*2)     //  4,718,592
#define OFF_H    (OFF_WHPK + (size_t)4*H_*H_*2)     //    786,432  h dbuf [2][8g][32][768] bf16
#define OFF_HT   (OFF_H + (size_t)2*B_*H_*2)        //    786,432  final h f32
#define OFF_BAR  (OFF_HT + (size_t)B_*H_*4)         //     65,536
#define OFF_END  (OFF_BAR + 65536)                  // ~43 MB total
// bar[] u32 map: flags [(g*32+s)*16] in [0,4096); xcc publish [4096,4352);
// init counter [5120]; tokens [8192 + blk*16]

__device__ __forceinline__ unsigned short f2bf(float f) {
  union { float f; unsigned u; } v; v.f = f;
  unsigned r = (v.u + 0x7fffu + ((v.u >> 16) & 1u)) >> 16;  // RNE
  return (unsigned short)r;
}
__device__ __forceinline__ float sigf(float x) {
  return __builtin_amdgcn_rcpf(1.0f + __expf(-x));
}
__device__ __forceinline__ float tanhf_(float x) {
  return 2.0f * __builtin_amdgcn_rcpf(1.0f + __expf(-2.0f * x)) - 1.0f;
}
__device__ __forceinline__ void gload16(const void* g, void* l) {
  __builtin_amdgcn_global_load_lds(
      (const __attribute__((address_space(1))) unsigned int*)g,
      (__attribute__((address_space(3))) unsigned int*)l, 16, 0, 0);
}
// 16B load, L1-bypass; SC1 adds L2-bypass (coherence point) for the fallback path
template<int OFF, bool SC1>
__device__ __forceinline__ u32x4 ld16(const void* p) {
  u32x4 r;
  if constexpr (SC1)
    asm volatile("global_load_dwordx4 %0, %1, off offset:%c2 sc0 sc1"
                 : "=v"(r) : "v"(p), "i"(OFF) : "memory");
  else
    asm volatile("global_load_dwordx4 %0, %1, off offset:%c2 sc0"
                 : "=v"(r) : "v"(p), "i"(OFF) : "memory");
  return r;
}
template<bool SC1>
__device__ __forceinline__ unsigned ld4w(const unsigned* p) {  // load + wait
  unsigned r;
  if constexpr (SC1)
    asm volatile("global_load_dword %0, %1, off sc0 sc1\n\ts_waitcnt vmcnt(0)"
                 : "=v"(r) : "v"(p) : "memory");
  else
    asm volatile("global_load_dword %0, %1, off sc0\n\ts_waitcnt vmcnt(0)"
                 : "=v"(r) : "v"(p) : "memory");
  return r;
}
template<bool SC1>
__device__ __forceinline__ void st2(ushort* p, unsigned v) {
  if constexpr (SC1)
    asm volatile("global_store_short %0, %1, off sc0 sc1" :: "v"(p), "v"(v) : "memory");
  else
    asm volatile("global_store_short %0, %1, off sc0" :: "v"(p), "v"(v) : "memory");
}
template<bool SC1>
__device__ __forceinline__ void st4(unsigned* p, unsigned v) {
  if constexpr (SC1)
    asm volatile("global_store_dword %0, %1, off sc0 sc1" :: "v"(p), "v"(v) : "memory");
  else
    asm volatile("global_store_dword %0, %1, off sc0" :: "v"(p), "v"(v) : "memory");
}

// ---------------- phase A: pack/convert + init ----------------
__global__ void prep_kernel(const float* __restrict__ x,
                            const float* __restrict__ wihf,
                            const float* __restrict__ whhf,
                            uint8_t* __restrict__ ws) {
  ushort* xpk = (ushort*)(ws + OFF_XPK);
  ushort* wipk = (ushort*)(ws + OFF_WIPK);
  ushort* whpk = (ushort*)(ws + OFF_WHPK);
  unsigned* bar = (unsigned*)(ws + OFF_BAR);
  const size_t tid = (size_t)blockIdx.x * blockDim.x + threadIdx.x;
  const size_t nth = (size_t)gridDim.x * blockDim.x;

  // x -> frag-packed (groups of 32 batch rows, 2 m-tiles of 16)
  for (size_t c = tid; c < (size_t)T_*B_*D_/8; c += nth) {
    const unsigned row = (unsigned)(c >> 6);     // t*256 + b
    const unsigned j = (unsigned)c & 63u;        // 16B chunk within row (k = j*8)
    const unsigned t = row >> 8, b = row & 255u;
    const float4 v0 = ((const float4*)x)[c*2];
    const float4 v1 = ((const float4*)x)[c*2+1];
    ushort4 o0, o1;
    o0.x=f2bf(v0.x); o0.y=f2bf(v0.y); o0.z=f2bf(v0.z); o0.w=f2bf(v0.w);
    o1.x=f2bf(v1.x); o1.y=f2bf(v1.y); o1.z=f2bf(v1.z); o1.w=f2bf(v1.w);
    const size_t dst = ((size_t)(((t*8u + (b>>5))*2u + ((b>>4)&1u))*16u + (j>>2))*64u
                        + (j&3u)*16u + (b&15u)) * 8u;
    *(ushort4*)(xpk + dst)     = o0;
    *(ushort4*)(xpk + dst + 4) = o1;
  }
  // W_ih -> frag-packed per strip: chunk ((s*16+kf)*6+nt)*64+L
  for (size_t c = tid; c < (size_t)196608; c += nth) {
    const unsigned L = (unsigned)c & 63u;
    const unsigned r1 = (unsigned)(c >> 6);
    const unsigned nt = r1 % 6u, r2 = r1 / 6u;
    const unsigned kf = r2 & 15u, s = r2 >> 4;
    const unsigned i = nt*16u + (L & 15u);
    const unsigned G = (i & 3u)*768u + s*24u + (i >> 2);
    const unsigned k0 = kf*32u + (L >> 4)*8u;
    const float4 v0 = *(const float4*)(wihf + (size_t)G*512u + k0);
    const float4 v1 = *(const float4*)(wihf + (size_t)G*512u + k0 + 4);
    ushort4 o0, o1;
    o0.x=f2bf(v0.x); o0.y=f2bf(v0.y); o0.z=f2bf(v0.z); o0.w=f2bf(v0.w);
    o1.x=f2bf(v1.x); o1.y=f2bf(v1.y); o1.z=f2bf(v1.z); o1.w=f2bf(v1.w);
    *(ushort4*)(wipk + c*8)     = o0;
    *(ushort4*)(wipk + c*8 + 4) = o1;
  }
  // W_hh -> frag-packed per strip: chunk ((s*24+kf)*6+nt)*64+L
  for (size_t c = tid; c < (size_t)294912; c += nth) {
    const unsigned L = (unsigned)c & 63u;
    const unsigned r1 = (unsigned)(c >> 6);
    const unsigned nt = r1 % 6u, r2 = r1 / 6u;
    const unsigned kf = r2 % 24u, s = r2 / 24u;
    const unsigned i = nt*16u + (L & 15u);
    const unsigned G = (i & 3u)*768u + s*24u + (i >> 2);
    const unsigned k0 = kf*32u + (L >> 4)*8u;
    const float4 v0 = *(const float4*)(whhf + (size_t)G*768u + k0);
    const float4 v1 = *(const float4*)(whhf + (size_t)G*768u + k0 + 4);
    ushort4 o0, o1;
    o0.x=f2bf(v0.x); o0.y=f2bf(v0.y); o0.z=f2bf(v0.z); o0.w=f2bf(v0.w);
    o1.x=f2bf(v1.x); o1.y=f2bf(v1.y); o1.z=f2bf(v1.z); o1.w=f2bf(v1.w);
    *(ushort4*)(whpk + c*8)     = o0;
    *(ushort4*)(whpk + c*8 + 4) = o1;
  }
  for (size_t i = tid; i < 16384; i += nth) bar[i] = 0u;  // flags/xcc/counter/tokens
}

// ---------------- phase C: persistent recurrence, intra-XCD ----------------
// grid 256 = #CUs, 1 WG/CU (157KB LDS). g=blk&7: 32 batch rows; s=blk>>3: 24 h-cols.
// W_hh slice LDS-resident. h + flags through the XCD's L2 (sc0) in the local path.
template<bool SC1>
__device__ __forceinline__ void run_loop(uint8_t* ws, const ushort* whh_lds, float* gbuf,
                                         const float* bih, const float* bhh,
                                         int tid, int g, int s) {
  const int lane = tid & 63, w = tid >> 6, wq = w & 1, wm = w >> 1;
  const u32x4* xpkv = (const u32x4*)(ws + OFF_XPK);
  const u32x4* wipkv = (const u32x4*)(ws + OFF_WIPK);
  ushort* hb = (ushort*)(ws + OFF_H);
  float* hT = (float*)(ws + OFF_HT);
  unsigned* bar = (unsigned*)(ws + OFF_BAR);
  float* gw = gbuf + w*816;                    // wave-local gate xpose region (stride 17)

  float bias[3][4];
  #pragma unroll
  for (int j = 0; j < 3; ++j) {
    const int col = s*24 + wq*12 + (lane >> 4) + 4*j;
    #pragma unroll
    for (int q = 0; q < 4; ++q) bias[j][q] = bih[q*H_ + col] + bhh[q*H_ + col];
  }
  const unsigned* fp = bar + (size_t)(g*32 + ((lane < 32) ? lane : 31)) * 16;

  f32x4 acc[3];
  float cc[3] = {0.f, 0.f, 0.f};

  auto xproj = [&](int tt) {   // acc = x(tt) @ W_ih^T for this wave's 3 N-tiles
    #pragma unroll
    for (int n = 0; n < 3; ++n) acc[n] = (f32x4){0.f,0.f,0.f,0.f};
    const u32x4* xb2 = xpkv + ((((size_t)tt*8 + g)*2 + wm)*16)*64 + lane;
    const u32x4* wb2 = wipkv + ((size_t)(s*96 + wq*3))*64 + lane;
    #pragma unroll
    for (int kf = 0; kf < 16; ++kf) {
      const u32x4 xr = xb2[kf*64];
      const bf16x8 xa = *(const bf16x8*)&xr;
      #pragma unroll
      for (int n = 0; n < 3; ++n) {
        const u32x4 wr = wb2[(kf*6 + n)*64];
        acc[n] = __builtin_amdgcn_mfma_f32_16x16x32_bf16(xa, *(const bf16x8*)&wr, acc[n], 0, 0, 0);
      }
    }
  };

  xproj(0);
  #pragma unroll 1
  for (int t = 0; t < T_; ++t) {
    if (t > 0) {
      if (w == 0) {                              // wait: all 32 strips posted h(t)
        while (1) {
          const unsigned v = ld4w<SC1>(fp);
          if (__all((int)(v >= (unsigned)t))) break;
          __builtin_amdgcn_s_sleep(1);
        }
      }
      __syncthreads();
      // h A-frags: 24 x 16B L2-local loads, one base, one round trip
      const ushort* hr = hb + ((size_t)(t & 1)*8 + g)*((size_t)32*H_)
                         + (size_t)(wm*16 + (lane & 15))*H_ + (lane >> 4)*8;
      u32x4 ah[24];
      #define LH(i) ah[i] = ld16<(i)*64, SC1>(hr)
      LH(0); LH(1); LH(2); LH(3); LH(4); LH(5); LH(6); LH(7);
      LH(8); LH(9); LH(10); LH(11); LH(12); LH(13); LH(14); LH(15);
      LH(16); LH(17); LH(18); LH(19); LH(20); LH(21); LH(22); LH(23);
      #undef LH
      asm volatile("s_waitcnt vmcnt(0)" ::: "memory");
      __builtin_amdgcn_sched_barrier(0);
      #pragma unroll
      for (int kf = 0; kf < 24; ++kf) {
        const bf16x8 a = *(const bf16x8*)&ah[kf];
        #pragma unroll
        for (int n = 0; n < 3; ++n) {
          const bf16x8 b = *(const bf16x8*)(whh_lds + (size_t)((kf*6 + wq*3 + n)*64 + lane)*8);
          acc[n] = __builtin_amdgcn_mfma_f32_16x16x32_bf16(a, b, acc[n], 0, 0, 0);
        }
      }
    }
    // gate xpose (wave-local LDS, no barrier) + activations
    #pragma unroll
    for (int n = 0; n < 3; ++n)
      #pragma unroll
      for (int r = 0; r < 4; ++r)
        gw[(n*16 + (lane & 15))*17 + (lane >> 4)*4 + r] = acc[n][r];
    float hv[3];
    #pragma unroll
    for (int j = 0; j < 3; ++j) {
      const int cl = (lane >> 4) + 4*j;
      const float g0 = gw[(cl*4+0)*17 + (lane & 15)];
      const float g1 = gw[(cl*4+1)*17 + (lane & 15)];
      const float g2 = gw[(cl*4+2)*17 + (lane & 15)];
      const float g3 = gw[(cl*4+3)*17 + (lane & 15)];
      const float iv = sigf(g0 + bias[j][0]);
      const float fv = sigf(g1 + bias[j][1]);
      const float gv = tanhf_(g2 + bias[j][2]);
      const float ov = sigf(g3 + bias[j][3]);
      const float cn = fv*cc[j] + iv*gv;
      cc[j] = cn;
      hv[j] = ov * tanhf_(cn);
    }
    const int rowl = wm*16 + (lane & 15);
    if (t == T_-1) {
      #pragma unroll
      for (int j = 0; j < 3; ++j) {
        const int col = s*24 + wq*12 + (lane >> 4) + 4*j;
        hT[(size_t)(g*32 + rowl)*H_ + col] = hv[j];
      }
      break;
    }
    ushort* hn = hb + ((size_t)((t+1) & 1)*8 + g)*((size_t)32*H_);
    #pragma unroll
    for (int j = 0; j < 3; ++j) {
      const int col = s*24 + wq*12 + (lane >> 4) + 4*j;
      st2<SC1>(hn + (size_t)rowl*H_ + col, (unsigned)f2bf(hv[j]));
    }
    asm volatile("s_waitcnt vmcnt(0)" ::: "memory");   // h stores acked (L2 / coh pt)
    __syncthreads();
    if (tid == 0) st4<SC1>(bar + (size_t)(g*32 + s)*16, (unsigned)(t + 1));
    xproj(t + 1);                                       // under the barrier slack
  }
}

__global__ __launch_bounds__(256, 1) void lstm_kernel(uint8_t* __restrict__ ws,
                                                      const float* __restrict__ bih,
                                                      const float* __restrict__ bhh) {
  __shared__ ushort whh_lds[73728];   // 144 KB: [kf 24][nt 6][64] 16B frag chunks
  __shared__ float gbuf[3264];        // 12.75 KB: 4 waves x [i 48][m 16] stride 17
  const int tid = threadIdx.x, lane = tid & 63, w = tid >> 6;
  const int g = blockIdx.x & 7, s = blockIdx.x >> 3;
  unsigned* bar = (unsigned*)(ws + OFF_BAR);

  // W_hh strip -> LDS (frag-ordered, contiguous stream via global_load_lds)
  const uint8_t* wsrc = ws + OFF_WHPK + (size_t)s*9216*16;
  #pragma unroll
  for (int i = 0; i < 36; ++i) {
    const int cb = (w*36 + i)*64;               // wave-uniform chunk base
    gload16(wsrc + (size_t)(cb + lane)*16, (uint8_t*)whh_lds + (size_t)cb*16);
  }

  // discover XCD + co-location probe (token tests sc0 write visibility)
  const unsigned xcd = __builtin_amdgcn_s_getreg((3 << 11) | 20) & 7u;  // HW_REG_XCC_ID
  if (tid == 0) {
    unsigned one = 1u;
    asm volatile("global_store_dword %0, %1, off sc0" :: "v"(bar + 8192 + blockIdx.x*16), "v"(one) : "memory");
    asm volatile("global_store_dword %0, %1, off sc0 sc1" :: "v"(bar + 4096 + blockIdx.x), "v"(xcd) : "memory");
    asm volatile("s_waitcnt vmcnt(0)" ::: "memory");
    __hip_atomic_fetch_add(bar + 5120, 1u, __ATOMIC_RELAXED, __HIP_MEMORY_SCOPE_SYSTEM);
    while (__hip_atomic_load(bar + 5120, __ATOMIC_RELAXED, __HIP_MEMORY_SCOPE_SYSTEM) < 256u)
      __builtin_amdgcn_s_sleep(2);
  }
  __syncthreads();
  const int pl = (lane < 32) ? lane : 31;
  const unsigned oxcc = ld4w<true >(bar + 4096 + g + 8*pl);
  const unsigned otok = ld4w<false>(bar + 8192 + (size_t)(g + 8*pl)*16);
  const bool local = __all((int)(oxcc == xcd)) && __all((int)(otok == 1u));

  asm volatile("s_waitcnt vmcnt(0) lgkmcnt(0)" ::: "memory");
  __syncthreads();                                 // whh_lds fully loaded

  if (local) run_loop<false>(ws, whh_lds, gbuf, bih, bhh, tid, g, s);
  else       run_loop<true >(ws, whh_lds, gbuf, bih, bhh, tid, g, s);
}

// ---------------- phase D: out = h_T @ W_fc^T + b_fc ----------------
__global__ __launch_bounds__(64) void fc_kernel(const uint8_t* __restrict__ ws,
                                                const float* __restrict__ wfc,
                                                const float* __restrict__ bfc,
                                                float* __restrict__ out) {
  const float* hT = (const float*)(ws + OFF_HT);
  const int b = blockIdx.x;
  const int lane = threadIdx.x;
  const float* hr = hT + (size_t)b*H_;
  float hv[12];
  #pragma unroll
  for (int i = 0; i < 12; ++i) hv[i] = hr[lane + i*64];
  for (int o = 0; o < OUT_; ++o) {
    const float* wr = wfc + (size_t)o*H_;
    float sum = 0.f;
    #pragma unroll
    for (int i = 0; i < 12; ++i) sum += hv[i] * wr[lane + i*64];
    #pragma unroll
    for (int off = 32; off; off >>= 1) sum += __shfl_xor(sum, off);
    if (lane == 0) out[(size_t)b*OUT_ + o] = sum + bfc[o];
  }
}

extern "C" void kernel_launch(void* const* d_in, const int* in_sizes, int n_in,
                              void* d_out, int out_size, void* d_ws, size_t ws_size,
                              hipStream_t stream) {
  const float* x   = (const float*)d_in[0];
  const float* wih = (const float*)d_in[1];
  const float* whh = (const float*)d_in[2];
  const float* bih = (const float*)d_in[3];
  const float* bhh = (const float*)d_in[4];
  const float* wfc = (const float*)d_in[5];
  const float* bfc = (const float*)d_in[6];
  uint8_t* ws = (uint8_t*)d_ws;
  float* out = (float*)d_out;

  prep_kernel<<<dim3(2048), dim3(256), 0, stream>>>(x, wih, whh, ws);
  lstm_kernel<<<dim3(256), dim3(256), 0, stream>>>(ws, bih, bhh);
  fc_kernel<<<dim3(256), dim3(64), 0, stream>>>(ws, wfc, bfc, out);
}

// Round 7
// 994.036 us; speedup vs baseline: 1.5016x; 1.1478x over previous
//
#include <hip/hip_runtime.h>
#include <stdint.h>

#define T_ 128
#define B_ 256
#define D_ 512
#define H_ 768
#define NG 3072   // 4*H
#define OUT_ 60

using bf16x8 = __attribute__((ext_vector_type(8))) __bf16;
using f32x4  = __attribute__((ext_vector_type(4))) float;
using u32x4  = __attribute__((ext_vector_type(4))) unsigned int;

// ---------------- ws layout (bytes) ----------------
#define OFF_XB   ((size_t)0)                        // x bf16 linear [T*B][D]
#define OFF_WI   (OFF_XB + (size_t)T_*B_*D_*2)      // W_ih bf16 linear [NG][D]
#define OFF_WHPK (OFF_WI + (size_t)NG*D_*2)         // W_hh frag-packed per strip
#define OFF_H    (OFF_WHPK + (size_t)NG*H_*2)       // h dbuf [2][8g][32][768] bf16
#define OFF_HT   (OFF_H + (size_t)2*B_*H_*2)        // final h f32
#define OFF_BAR  (OFF_HT + (size_t)B_*H_*4)         // flags/probe, 64KB
#define OFF_XP   (OFF_BAR + 65536)                  // xp row-major [T*B][NG] bf16, 201MB
#define OFF_END  (OFF_XP + (size_t)T_*B_*NG*2)
// bar[] u32 map: flags [(g*32+s)*16]; xcc publish [4096+blk]; init ctr [5120]

__device__ __forceinline__ unsigned short f2bf(float f) {
  union { float f; unsigned u; } v; v.f = f;
  unsigned r = (v.u + 0x7fffu + ((v.u >> 16) & 1u)) >> 16;  // RNE
  return (unsigned short)r;
}
__device__ __forceinline__ float sigf(float x) {
  return __builtin_amdgcn_rcpf(1.0f + __expf(-x));
}
__device__ __forceinline__ float tanhf_(float x) {
  return 2.0f * __builtin_amdgcn_rcpf(1.0f + __expf(-2.0f * x)) - 1.0f;
}
__device__ __forceinline__ void gload16(const void* g, void* l) {
  __builtin_amdgcn_global_load_lds(
      (const __attribute__((address_space(1))) unsigned int*)g,
      (__attribute__((address_space(3))) unsigned int*)l, 16, 0, 0);
}
template<int OFF, bool SC1>
__device__ __forceinline__ u32x4 ld16(const void* p) {
  u32x4 r;
  if constexpr (SC1)
    asm volatile("global_load_dwordx4 %0, %1, off offset:%c2 sc0 sc1"
                 : "=v"(r) : "v"(p), "i"(OFF) : "memory");
  else
    asm volatile("global_load_dwordx4 %0, %1, off offset:%c2 sc0"
                 : "=v"(r) : "v"(p), "i"(OFF) : "memory");
  return r;
}
// coherent 4B load+wait (coherence point) — used for ALL flag polls
__device__ __forceinline__ unsigned ld4coh(const unsigned* p) {
  unsigned r;
  asm volatile("global_load_dword %0, %1, off sc0 sc1\n\ts_waitcnt vmcnt(0)"
               : "=v"(r) : "v"(p) : "memory");
  return r;
}
template<bool SC1>
__device__ __forceinline__ void st2(ushort* p, unsigned v) {
  if constexpr (SC1)
    asm volatile("global_store_short %0, %1, off sc0 sc1" :: "v"(p), "v"(v) : "memory");
  else
    asm volatile("global_store_short %0, %1, off sc0" :: "v"(p), "v"(v) : "memory");
}
__device__ __forceinline__ void st4coh(unsigned* p, unsigned v) {
  asm volatile("global_store_dword %0, %1, off sc0 sc1" :: "v"(p), "v"(v) : "memory");
}

// ---------------- phase A: convert + pack + init ----------------
__global__ void prep_kernel(const float* __restrict__ x,
                            const float* __restrict__ wihf,
                            const float* __restrict__ whhf,
                            uint8_t* __restrict__ ws) {
  ushort* xb = (ushort*)(ws + OFF_XB);
  ushort* wi = (ushort*)(ws + OFF_WI);
  ushort* whpk = (ushort*)(ws + OFF_WHPK);
  unsigned* bar = (unsigned*)(ws + OFF_BAR);
  const size_t tid = (size_t)blockIdx.x * blockDim.x + threadIdx.x;
  const size_t nth = (size_t)gridDim.x * blockDim.x;

  for (size_t i = tid; i < (size_t)T_*B_*D_/4; i += nth) {
    float4 v = ((const float4*)x)[i];
    ushort4 o; o.x=f2bf(v.x); o.y=f2bf(v.y); o.z=f2bf(v.z); o.w=f2bf(v.w);
    ((ushort4*)xb)[i] = o;
  }
  for (size_t i = tid; i < (size_t)NG*D_/4; i += nth) {
    float4 v = ((const float4*)wihf)[i];
    ushort4 o; o.x=f2bf(v.x); o.y=f2bf(v.y); o.z=f2bf(v.z); o.w=f2bf(v.w);
    ((ushort4*)wi)[i] = o;
  }
  // W_hh -> frag-packed per strip: chunk ((s*24+kf)*6+nt)*64+L  (verified R5)
  for (size_t c = tid; c < (size_t)294912; c += nth) {
    const unsigned L = (unsigned)c & 63u;
    const unsigned r1 = (unsigned)(c >> 6);
    const unsigned nt = r1 % 6u, r2 = r1 / 6u;
    const unsigned kf = r2 % 24u, s = r2 / 24u;
    const unsigned i = nt*16u + (L & 15u);
    const unsigned G = (i & 3u)*768u + s*24u + (i >> 2);
    const unsigned k0 = kf*32u + (L >> 4)*8u;
    const float4 v0 = *(const float4*)(whhf + (size_t)G*768u + k0);
    const float4 v1 = *(const float4*)(whhf + (size_t)G*768u + k0 + 4);
    ushort4 o0, o1;
    o0.x=f2bf(v0.x); o0.y=f2bf(v0.y); o0.z=f2bf(v0.z); o0.w=f2bf(v0.w);
    o1.x=f2bf(v1.x); o1.y=f2bf(v1.y); o1.z=f2bf(v1.z); o1.w=f2bf(v1.w);
    *(ushort4*)(whpk + c*8)     = o0;
    *(ushort4*)(whpk + c*8 + 4) = o1;
  }
  for (size_t i = tid; i < 16384; i += nth) bar[i] = 0u;
}

// ---------------- phase B: xp = x @ W_ih^T (128x128 tile, BK=64; verified R2) ----------------
__global__ __launch_bounds__(256) void xproj_kernel(uint8_t* __restrict__ ws) {
  const ushort* __restrict__ xb = (const ushort*)(ws + OFF_XB);
  const ushort* __restrict__ wi = (const ushort*)(ws + OFF_WI);
  ushort* __restrict__ xp = (ushort*)(ws + OFF_XP);

  __shared__ ushort smA[128*64];
  __shared__ ushort smB[128*64];

  const int tid = threadIdx.x;
  const int lane = tid & 63;
  const int w = tid >> 6;
  const int bn = blockIdx.x % 24;
  const int bm = blockIdx.x / 24;
  const int m0 = bm * 128, n0 = bn * 128;
  const int mi = (w >> 1) * 64, ni = (w & 1) * 64;

  f32x4 acc[4][4] = {};

  for (int k0 = 0; k0 < D_; k0 += 64) {
    __syncthreads();
    #pragma unroll
    for (int i = 0; i < 4; ++i) {
      const int ig = w*4 + i;
      const int o  = ig*1024 + lane*16;
      const int row = o >> 7;
      const int colB = o & 127;
      const int scol = colB ^ ((row & 7) << 4);
      gload16((const uint8_t*)xb + ((size_t)(m0+row)*D_ + k0)*2 + scol,
              (uint8_t*)smA + ig*1024);
      gload16((const uint8_t*)wi + ((size_t)(n0+row)*D_ + k0)*2 + scol,
              (uint8_t*)smB + ig*1024);
    }
    __syncthreads();
    #pragma unroll
    for (int kk = 0; kk < 2; ++kk) {
      const int colB = kk*64 + (lane >> 4)*16;
      bf16x8 a[4], b[4];
      #pragma unroll
      for (int mt = 0; mt < 4; ++mt) {
        const int row = mi + mt*16 + (lane & 15);
        a[mt] = *(const bf16x8*)((const uint8_t*)smA + row*128 + (colB ^ ((row & 7) << 4)));
      }
      #pragma unroll
      for (int nt = 0; nt < 4; ++nt) {
        const int row = ni + nt*16 + (lane & 15);
        b[nt] = *(const bf16x8*)((const uint8_t*)smB + row*128 + (colB ^ ((row & 7) << 4)));
      }
      #pragma unroll
      for (int mt = 0; mt < 4; ++mt)
        #pragma unroll
        for (int nt = 0; nt < 4; ++nt)
          acc[mt][nt] = __builtin_amdgcn_mfma_f32_16x16x32_bf16(a[mt], b[nt], acc[mt][nt], 0, 0, 0);
    }
  }
  #pragma unroll
  for (int mt = 0; mt < 4; ++mt)
    #pragma unroll
    for (int nt = 0; nt < 4; ++nt) {
      const int r0 = m0 + mi + mt*16 + (lane >> 4)*4;
      const int c  = n0 + ni + nt*16 + (lane & 15);
      #pragma unroll
      for (int r = 0; r < 4; ++r)
        xp[(size_t)(r0 + r)*NG + c] = f2bf(acc[mt][nt][r]);
    }
}

// ---------------- phase C: persistent recurrence, intra-XCD h, coherent flags ----------------
template<bool SC1>
__device__ __forceinline__ void run_loop(uint8_t* ws, const ushort* whh_lds, float* gbuf,
                                         const float* bih, const float* bhh,
                                         int tid, int g, int s) {
  const int lane = tid & 63, w = tid >> 6, wq = w & 1, wm = w >> 1;
  const int l15 = lane & 15, hi = lane >> 4;
  ushort* hb = (ushort*)(ws + OFF_H);
  const ushort* xp = (const ushort*)(ws + OFF_XP);
  float* hT = (float*)(ws + OFF_HT);
  unsigned* bar = (unsigned*)(ws + OFF_BAR);
  float* gw = gbuf + w*816;

  float bias[3][4];
  #pragma unroll
  for (int j = 0; j < 3; ++j) {
    const int col = s*24 + wq*12 + hi + 4*j;
    #pragma unroll
    for (int q = 0; q < 4; ++q) bias[j][q] = bih[q*H_ + col] + bhh[q*H_ + col];
  }
  const unsigned* fp = bar + (size_t)(g*32 + ((lane < 32) ? lane : 31)) * 16;

  // per-thread xp source: row = g*32+wm*16+l15, cols q*768 + s*24+wq*12+hi (+4j)
  const ushort* xpb = xp + (size_t)(g*32 + wm*16 + l15)*NG + s*24 + wq*12 + hi;
  ushort xq[12];   // [q][j], plain loads (compiler-managed waitcnt)
  {
    const ushort* p = xpb;
    #pragma unroll
    for (int q = 0; q < 4; ++q)
      #pragma unroll
      for (int j = 0; j < 3; ++j)
        xq[q*3+j] = p[q*768 + 4*j];
  }

  float cc[3] = {0.f, 0.f, 0.f};

  #pragma unroll 1
  for (int t = 0; t < T_; ++t) {
    f32x4 acc[3] = {};
    if (t > 0) {
      if (w == 0) {                              // wait: all 32 strips posted h(t)
        while (1) {
          const unsigned v = ld4coh(fp);         // coherence-point poll: livelock-free
          if (__all((int)(v >= (unsigned)t))) break;
          __builtin_amdgcn_s_sleep(1);
        }
      }
      __syncthreads();
      // h A-frags: 24 x 16B loads (L2-local in intra-XCD mode)
      const ushort* hr = hb + ((size_t)(t & 1)*8 + g)*((size_t)32*H_)
                         + (size_t)(wm*16 + l15)*H_ + hi*8;
      u32x4 ah[24];
      #define LH(i) ah[i] = ld16<(i)*64, SC1>(hr)
      LH(0); LH(1); LH(2); LH(3); LH(4); LH(5); LH(6); LH(7);
      LH(8); LH(9); LH(10); LH(11); LH(12); LH(13); LH(14); LH(15);
      LH(16); LH(17); LH(18); LH(19); LH(20); LH(21); LH(22); LH(23);
      #undef LH
      asm volatile("s_waitcnt vmcnt(0)" ::: "memory");
      __builtin_amdgcn_sched_barrier(0);
      #pragma unroll
      for (int kf = 0; kf < 24; ++kf) {
        const bf16x8 a = *(const bf16x8*)&ah[kf];
        #pragma unroll
        for (int n = 0; n < 3; ++n) {
          const bf16x8 b = *(const bf16x8*)(whh_lds + (size_t)((kf*6 + wq*3 + n)*64 + lane)*8);
          acc[n] = __builtin_amdgcn_mfma_f32_16x16x32_bf16(a, b, acc[n], 0, 0, 0);
        }
      }
    }
    // gate xpose (wave-local LDS region, no barrier) + activations (+ xp + bias)
    #pragma unroll
    for (int n = 0; n < 3; ++n)
      #pragma unroll
      for (int r = 0; r < 4; ++r)
        gw[(n*16 + l15)*17 + hi*4 + r] = acc[n][r];
    float hv[3];
    #pragma unroll
    for (int j = 0; j < 3; ++j) {
      const int cl = hi + 4*j;
      float gq[4];
      #pragma unroll
      for (int q = 0; q < 4; ++q) {
        union { unsigned u; float f; } xv; xv.u = ((unsigned)xq[q*3 + j]) << 16;
        gq[q] = gw[(cl*4+q)*17 + l15] + xv.f + bias[j][q];
      }
      const float iv = sigf(gq[0]);
      const float fv = sigf(gq[1]);
      const float gv = tanhf_(gq[2]);
      const float ov = sigf(gq[3]);
      const float cn = fv*cc[j] + iv*gv;
      cc[j] = cn;
      hv[j] = ov * tanhf_(cn);
    }
    const int rowl = wm*16 + l15;
    if (t == T_-1) {
      #pragma unroll
      for (int j = 0; j < 3; ++j) {
        const int col = s*24 + wq*12 + hi + 4*j;
        hT[(size_t)(g*32 + rowl)*H_ + col] = hv[j];
      }
      break;
    }
    ushort* hn = hb + ((size_t)((t+1) & 1)*8 + g)*((size_t)32*H_);
    #pragma unroll
    for (int j = 0; j < 3; ++j) {
      const int col = s*24 + wq*12 + hi + 4*j;
      st2<SC1>(hn + (size_t)rowl*H_ + col, (unsigned)f2bf(hv[j]));
    }
    asm volatile("s_waitcnt vmcnt(0)" ::: "memory");   // h stores done (L2 / coh pt)
    __syncthreads();
    if (tid == 0) st4coh(bar + (size_t)(g*32 + s)*16, (unsigned)(t + 1));
    {  // prefetch xp(t+1) in the post-flag slack (plain loads)
      const ushort* p = xpb + (size_t)(t + 1)*B_*NG;
      #pragma unroll
      for (int q = 0; q < 4; ++q)
        #pragma unroll
        for (int j = 0; j < 3; ++j)
          xq[q*3+j] = p[q*768 + 4*j];
    }
  }
}

__global__ __launch_bounds__(256, 1) void lstm_kernel(uint8_t* __restrict__ ws,
                                                      const float* __restrict__ bih,
                                                      const float* __restrict__ bhh) {
  __shared__ ushort whh_lds[73728];   // 144 KB: [kf 24][nt 6][64] 16B frag chunks
  __shared__ float gbuf[3264];        // 12.75 KB
  const int tid = threadIdx.x, lane = tid & 63, w = tid >> 6;
  const int g = blockIdx.x & 7, s = blockIdx.x >> 3;
  unsigned* bar = (unsigned*)(ws + OFF_BAR);

  const uint8_t* wsrc = ws + OFF_WHPK + (size_t)s*9216*16;
  #pragma unroll
  for (int i = 0; i < 36; ++i) {
    const int cb = (w*36 + i)*64;
    gload16(wsrc + (size_t)(cb + lane)*16, (uint8_t*)whh_lds + (size_t)cb*16);
  }

  // publish XCC_ID (authoritative) via coherence point; one-time global barrier
  const unsigned xcd = __builtin_amdgcn_s_getreg((3 << 11) | 20) & 7u;  // HW_REG_XCC_ID
  if (tid == 0) {
    st4coh(bar + 4096 + blockIdx.x, xcd);
    asm volatile("s_waitcnt vmcnt(0)" ::: "memory");
    __hip_atomic_fetch_add(bar + 5120, 1u, __ATOMIC_RELAXED, __HIP_MEMORY_SCOPE_SYSTEM);
    while (__hip_atomic_load(bar + 5120, __ATOMIC_RELAXED, __HIP_MEMORY_SCOPE_SYSTEM) < 256u)
      __builtin_amdgcn_s_sleep(2);
  }
  __syncthreads();
  const int pl = (lane < 32) ? lane : 31;
  const unsigned oxcc = ld4coh(bar + 4096 + g + 8*pl);   // peers of my group
  const bool local = __all((int)(oxcc == xcd));

  asm volatile("s_waitcnt vmcnt(0) lgkmcnt(0)" ::: "memory");
  __syncthreads();                                 // whh_lds fully staged

  if (local) run_loop<false>(ws, whh_lds, gbuf, bih, bhh, tid, g, s);
  else       run_loop<true >(ws, whh_lds, gbuf, bih, bhh, tid, g, s);
}

// ---------------- phase D: out = h_T @ W_fc^T + b_fc ----------------
__global__ __launch_bounds__(64) void fc_kernel(const uint8_t* __restrict__ ws,
                                                const float* __restrict__ wfc,
                                                const float* __restrict__ bfc,
                                                float* __restrict__ out) {
  const float* hT = (const float*)(ws + OFF_HT);
  const int b = blockIdx.x;
  const int lane = threadIdx.x;
  const float* hr = hT + (size_t)b*H_;
  float hv[12];
  #pragma unroll
  for (int i = 0; i < 12; ++i) hv[i] = hr[lane + i*64];
  for (int o = 0; o < OUT_; ++o) {
    const float* wr = wfc + (size_t)o*H_;
    float sum = 0.f;
    #pragma unroll
    for (int i = 0; i < 12; ++i) sum += hv[i] * wr[lane + i*64];
    #pragma unroll
    for (int off = 32; off; off >>= 1) sum += __shfl_xor(sum, off);
    if (lane == 0) out[(size_t)b*OUT_ + o] = sum + bfc[o];
  }
}

extern "C" void kernel_launch(void* const* d_in, const int* in_sizes, int n_in,
                              void* d_out, int out_size, void* d_ws, size_t ws_size,
                              hipStream_t stream) {
  const float* x   = (const float*)d_in[0];
  const float* wih = (const float*)d_in[1];
  const float* whh = (const float*)d_in[2];
  const float* bih = (const float*)d_in[3];
  const float* bhh = (const float*)d_in[4];
  const float* wfc = (const float*)d_in[5];
  const float* bfc = (const float*)d_in[6];
  uint8_t* ws = (uint8_t*)d_ws;
  float* out = (float*)d_out;

  prep_kernel<<<dim3(2048), dim3(256), 0, stream>>>(x, wih, whh, ws);
  xproj_kernel<<<dim3(256*24), dim3(256), 0, stream>>>(ws);
  lstm_kernel<<<dim3(256), dim3(256), 0, stream>>>(ws, bih, bhh);
  fc_kernel<<<dim3(256), dim3(64), 0, stream>>>(ws, wfc, bfc, out);
}